// Round 7
// baseline (240.444 us; speedup 1.0000x reference)
//
#include <hip/hip_runtime.h>
#include <stdint.h>
#include <math.h>

typedef __attribute__((ext_vector_type(8))) short short8;
typedef __attribute__((ext_vector_type(4))) float f32x4;
typedef __attribute__((ext_vector_type(16))) float f32x16;

#define DEV __device__ __forceinline__

DEV unsigned short f2bf(float f) {
  union { float f; unsigned int u; } v; v.f = f;
  return (unsigned short)((v.u + 0x7FFFu + ((v.u >> 16) & 1u)) >> 16);
}

DEV unsigned int pkbf(float a, float b) {  // low16 = bf16(a), high16 = bf16(b)
  unsigned int r;
  asm("v_cvt_pk_bf16_f32 %0, %1, %2" : "=v"(r) : "v"(a), "v"(b));
  return r;
}

#if __has_builtin(__builtin_amdgcn_permlane32_swap)
DEV float redmax32(float v) {
  typedef __attribute__((ext_vector_type(2))) unsigned int uint2v;
  union { float f; unsigned int u; } c; c.f = v;
  uint2v r = __builtin_amdgcn_permlane32_swap(c.u, c.u, false, false);
  union { unsigned int u; float f; } a, b; a.u = r[0]; b.u = r[1];
  return fmaxf(a.f, b.f);
}
DEV float redsum32(float v) {
  typedef __attribute__((ext_vector_type(2))) unsigned int uint2v;
  union { float f; unsigned int u; } c; c.f = v;
  uint2v r = __builtin_amdgcn_permlane32_swap(c.u, c.u, false, false);
  union { unsigned int u; float f; } a, b; a.u = r[0]; b.u = r[1];
  return a.f + b.f;
}
#else
DEV float redmax32(float v) { return fmaxf(v, __shfl_xor(v, 32, 64)); }
DEV float redsum32(float v) { return v + __shfl_xor(v, 32, 64); }
#endif

DEV void gld16(const void* g, void* lds) {
  __builtin_amdgcn_global_load_lds(
      (const __attribute__((address_space(1))) unsigned int*)g,
      (__attribute__((address_space(3))) unsigned int*)lds, 16, 0, 0);
}

// ---------------- fp32 -> bf16 convert (8 elems/thread) ----------------
__global__ __launch_bounds__(256) void cvt_bf16_kernel(
    const float* __restrict__ in, unsigned short* __restrict__ out, int n) {
  int i = (blockIdx.x * 256 + threadIdx.x) * 8;
  if (i >= n) return;
  const float4 a = *(const float4*)(in + i);
  const float4 b = *(const float4*)(in + i + 4);
  short8 o;
  o[0] = (short)f2bf(a.x); o[1] = (short)f2bf(a.y);
  o[2] = (short)f2bf(a.z); o[3] = (short)f2bf(a.w);
  o[4] = (short)f2bf(b.x); o[5] = (short)f2bf(b.y);
  o[6] = (short)f2bf(b.z); o[7] = (short)f2bf(b.w);
  *(short8*)(out + i) = o;
}

// ------------- transpose fp32 (K x N) -> bf16 (N x K) ------------------
__global__ __launch_bounds__(256) void transpose_w_kernel(
    const float* __restrict__ in, unsigned short* __restrict__ out,
    int Kdim, int Ndim) {
  __shared__ float t[32][33];
  const int nb = blockIdx.x * 32, kb = blockIdx.y * 32;
  const int tx = threadIdx.x & 31, ty = threadIdx.x >> 5;  // ty 0..7
#pragma unroll
  for (int i = 0; i < 32; i += 8)
    t[ty + i][tx] = in[(size_t)(kb + ty + i) * Ndim + nb + tx];
  __syncthreads();
#pragma unroll
  for (int i = 0; i < 32; i += 8)
    out[(size_t)(nb + ty + i) * Kdim + kb + tx] = f2bf(t[tx][ty + i]);
}

// --------- transpose V (bh, s, 64) bf16 -> Vts (bh, 64, s') bf16 -------
// s' applies perm16 = swap bits 2,3 of (s mod 16) so that PV B-fragments
// are direct packs of the S^T D-fragment (no cross-lane exchange needed).
__global__ __launch_bounds__(256) void transpose_v_kernel(
    const unsigned short* __restrict__ V, unsigned short* __restrict__ Vt) {
  __shared__ __align__(16) unsigned short t[64][72];
  const int bh = blockIdx.y, s0 = blockIdx.x * 64;
  const int tid = threadIdx.x;
  const unsigned short* src = V + ((size_t)bh * 2048 + s0) * 64;
#pragma unroll
  for (int pass = 0; pass < 2; ++pass) {
    int r = (tid >> 3) + pass * 32;
    short8 v = *(const short8*)(src + r * 64 + (tid & 7) * 8);
    *(short8*)(&t[r][(tid & 7) * 8]) = v;
  }
  __syncthreads();
  unsigned short* dst = Vt + (size_t)bh * 64 * 2048 + s0;
#pragma unroll
  for (int pass = 0; pass < 2; ++pass) {
    int d = (tid >> 3) + pass * 32;
    int ss = (tid & 7) * 8;
    short8 v;
#pragma unroll
    for (int j = 0; j < 8; ++j) {
      const int u = ss + j;
      const int g = (u & ~12) | ((u & 4) << 1) | ((u & 8) >> 1);  // swap bits 2,3
      v[j] = (short)t[g][d];
    }
    *(short8*)(dst + (size_t)d * 2048 + ss) = v;
  }
}

// ---------------- GEMM: C(MxN) = A(MxK,bf16) * Bt(NxK,bf16)^T ----------
template<int M, int N, int K, int MODE>
__global__ __launch_bounds__(256)
void gemm_bt_kernel(const unsigned short* __restrict__ A,
                    const unsigned short* __restrict__ Bt,
                    unsigned short* __restrict__ Qd,
                    unsigned short* __restrict__ Kd,
                    unsigned short* __restrict__ Vd,
                    float* __restrict__ outC) {
  __shared__ __align__(16) unsigned short lsA[128 * 32];
  __shared__ __align__(16) unsigned short lsB[128 * 32];
  const int tid = threadIdx.x, wid = tid >> 6, lane = tid & 63;
  const int wr = wid >> 1, wc = wid & 1;
  const int m0 = blockIdx.y * 128, n0 = blockIdx.x * 128;

  f32x4 acc[4][4] = {};

  const int rA = lane >> 2, kA = (lane & 3) * 8;
  for (int kt = 0; kt < K / 32; ++kt) {
    __syncthreads();
#pragma unroll
    for (int c = 0; c < 2; ++c) {
      const int q = c * 4 + wid;
      gld16(A  + (size_t)(m0 + q * 16 + rA) * K + kt * 32 + kA, lsA + q * 512);
      gld16(Bt + (size_t)(n0 + q * 16 + rA) * K + kt * 32 + kA, lsB + q * 512);
    }
    __syncthreads();
    short8 af[4], bfr[4];
#pragma unroll
    for (int i = 0; i < 4; ++i) {
      af[i]  = *(const short8*)(lsA + (wr * 64 + i * 16 + (lane & 15)) * 32 + (lane >> 4) * 8);
      bfr[i] = *(const short8*)(lsB + (wc * 64 + i * 16 + (lane & 15)) * 32 + (lane >> 4) * 8);
    }
#pragma unroll
    for (int i = 0; i < 4; ++i)
#pragma unroll
      for (int j = 0; j < 4; ++j)
        acc[i][j] = __builtin_amdgcn_mfma_f32_16x16x32_bf16(af[i], bfr[j], acc[i][j], 0, 0, 0);
  }

#pragma unroll
  for (int i = 0; i < 4; ++i) {
#pragma unroll
    for (int j = 0; j < 4; ++j) {
      const int rbase = m0 + wr * 64 + i * 16 + (lane >> 4) * 4;
      const int col = n0 + wc * 64 + j * 16 + (lane & 15);
      if constexpr (MODE == 0) {
        const int which = col >> 10, h = (col >> 6) & 15, d = col & 63;
        unsigned short* dst = which == 0 ? Qd : (which == 1 ? Kd : Vd);
        // Q pre-scaled by rsqrt(hd)*log2(e) so attention uses exp2 directly
        const float scale = which == 0 ? 0.18033688f : 1.0f;
#pragma unroll
        for (int ii = 0; ii < 4; ++ii) {
          const int r = rbase + ii, b = r >> 11, s = r & 2047;
          dst[((size_t)(b * 16 + h) * 2048 + s) * 64 + d] = f2bf(acc[i][j][ii] * scale);
        }
      } else {
#pragma unroll
        for (int ii = 0; ii < 4; ++ii)
          outC[(size_t)(rbase + ii) * N + col] = acc[i][j][ii];
      }
    }
  }
}

// ---------------- causal flash attention, single q-tile per wave --------
// grid 1024 1-D. bh = id & 63 (XCD swizzle: all 16 walkers of a bh land on
// XCD bh%8 -> K/V L2-resident). Walker w = id >> 6 (0..15); its 4 waves own
// q-tiles {w, 31-w, 32+w, 63-w}: per-block tile sum = 130, uniform -> per-CU
// load balanced without barriers. One q-tile per wave halves register state
// vs the paired version (target 3 waves/SIMD). No LDS, no barriers.
// S^T = mfma(K,Q): lane owns q = q0+(lane&31); softmax lane-local
// (permlane32_swap). V perm16-interleaved so PV B-frag is a direct pack.
// Incremental K/V pointers avoid per-iter 64-bit address rebuilds.
template<bool MASK>
DEV void attn_step1(int kv0, int qend, const short8 kf[4], const short8 qf[4],
                    const short8 vf[4], float& m, float& l, f32x16 o[2],
                    int ql, int h) {
  f32x16 st = {};
#pragma unroll
  for (int ss = 0; ss < 4; ++ss)
    st = __builtin_amdgcn_mfma_f32_32x32x16_bf16(kf[ss], qf[ss], st, 0, 0, 0);
  if constexpr (MASK) {
#pragma unroll
    for (int r = 0; r < 16; ++r) {
      const int krow = (r & 3) + 8 * (r >> 2) + 4 * h;
      if (kv0 + krow > qend + ql) st[r] = -INFINITY;
    }
  }
  float pm = fmaxf(fmaxf(fmaxf(st[0], st[1]), fmaxf(st[2], st[3])),
                   fmaxf(fmaxf(st[4], st[5]), fmaxf(st[6], st[7])));
  pm = fmaxf(pm, fmaxf(fmaxf(fmaxf(st[8], st[9]), fmaxf(st[10], st[11])),
                       fmaxf(fmaxf(st[12], st[13]), fmaxf(st[14], st[15]))));
  pm = redmax32(pm);
  if (!__all(pm <= m + 11.5f)) {       // defer-max (log2 units)
    const float mn = fmaxf(m, pm);
    const float al = exp2f(m - mn);
    m = mn;
    l *= al;
#pragma unroll
    for (int r = 0; r < 16; ++r) { o[0][r] *= al; o[1][r] *= al; }
  }
  float p[16];
#pragma unroll
  for (int r = 0; r < 16; ++r) p[r] = exp2f(st[r] - m);
  float ps = ((p[0] + p[1]) + (p[2] + p[3])) + ((p[4] + p[5]) + (p[6] + p[7]));
  ps += ((p[8] + p[9]) + (p[10] + p[11])) + ((p[12] + p[13]) + (p[14] + p[15]));
  l += redsum32(ps);
  union { unsigned int u[4]; short8 s8; } f0, f1;
#pragma unroll
  for (int i = 0; i < 4; ++i) {
    f0.u[i] = pkbf(p[2 * i], p[2 * i + 1]);
    f1.u[i] = pkbf(p[8 + 2 * i], p[9 + 2 * i]);
  }
  o[0] = __builtin_amdgcn_mfma_f32_32x32x16_bf16(vf[0], f0.s8, o[0], 0, 0, 0);
  o[0] = __builtin_amdgcn_mfma_f32_32x32x16_bf16(vf[1], f1.s8, o[0], 0, 0, 0);
  o[1] = __builtin_amdgcn_mfma_f32_32x32x16_bf16(vf[2], f0.s8, o[1], 0, 0, 0);
  o[1] = __builtin_amdgcn_mfma_f32_32x32x16_bf16(vf[3], f1.s8, o[1], 0, 0, 0);
}

__global__ __launch_bounds__(256, 3)
void attn_kernel(const unsigned short* __restrict__ Q,
                 const unsigned short* __restrict__ Kc,
                 const unsigned short* __restrict__ Vts,
                 unsigned short* __restrict__ O) {
  const int bh = blockIdx.x & 63;
  const int w  = blockIdx.x >> 6;            // 0..15
  const int wid = threadIdx.x >> 6, lane = threadIdx.x & 63;
  const int ql = lane & 31, h = lane >> 5;
  // per-block tile sum uniform: {w+1, 32-w, 33+w, 64-w} sums to 130
  const int qt = (wid == 0) ? w : (wid == 1) ? 31 - w : (wid == 2) ? 32 + w : 63 - w;
  const int q0 = qt * 32;

  const unsigned short* Qb = Q   + (size_t)bh * 2048 * 64;
  const unsigned short* Vb = Vts + (size_t)bh * 64 * 2048;

  short8 qf[4];
#pragma unroll
  for (int s = 0; s < 4; ++s)
    qf[s] = *(const short8*)(Qb + (size_t)(q0 + ql) * 64 + s * 16 + h * 8);

  f32x16 o[2] = {};                  // O^T: col q, rows d (two d-halves)
  float m = -INFINITY, l = 0.f;

  // incremental pointers (advance per tile: K +32 rows, V +32 cols)
  const unsigned short* kp  = Kc + (size_t)bh * 2048 * 64 + (size_t)ql * 64 + h * 8;
  const unsigned short* vp0 = Vb + (size_t)ql * 2048 + h * 8;
  const unsigned short* vp1 = vp0 + (size_t)32 * 2048;

  short8 kf[4], kn[4], vf[4];
#pragma unroll
  for (int s = 0; s < 4; ++s) kf[s] = *(const short8*)(kp + s * 16);

  for (int t = 0; t < qt; ++t) {
    const int kv0 = t * 32;
#pragma unroll
    for (int sl = 0; sl < 2; ++sl) {
      vf[sl]     = *(const short8*)(vp0 + sl * 16);
      vf[2 + sl] = *(const short8*)(vp1 + sl * 16);
    }
#pragma unroll
    for (int s = 0; s < 4; ++s) kn[s] = *(const short8*)(kp + 2048 + s * 16);
    attn_step1<false>(kv0, q0, kf, qf, vf, m, l, o, ql, h);
#pragma unroll
    for (int s = 0; s < 4; ++s) kf[s] = kn[s];
    kp += 2048; vp0 += 32; vp1 += 32;
  }
  // diagonal tile (masked, no prefetch)
  {
#pragma unroll
    for (int sl = 0; sl < 2; ++sl) {
      vf[sl]     = *(const short8*)(vp0 + sl * 16);
      vf[2 + sl] = *(const short8*)(vp1 + sl * 16);
    }
    attn_step1<true>(qt * 32, q0, kf, qf, vf, m, l, o, ql, h);
  }

  // epilogue: lane-local 1/l
  const float inv = 1.0f / l;
  const int b = bh >> 4, head = bh & 15;
  unsigned short* Orow = O + ((size_t)(b * 2048 + q0 + ql)) * 1024 + head * 64;
#pragma unroll
  for (int g = 0; g < 4; ++g) {
    {
      const unsigned int lo = pkbf(o[0][g * 4 + 0] * inv, o[0][g * 4 + 1] * inv);
      const unsigned int hi = pkbf(o[0][g * 4 + 2] * inv, o[0][g * 4 + 3] * inv);
      uint2 val; val.x = lo; val.y = hi;
      *(uint2*)(Orow + 8 * g + 4 * h) = val;
    }
    {
      const unsigned int lo = pkbf(o[1][g * 4 + 0] * inv, o[1][g * 4 + 1] * inv);
      const unsigned int hi = pkbf(o[1][g * 4 + 2] * inv, o[1][g * 4 + 3] * inv);
      uint2 val; val.x = lo; val.y = hi;
      *(uint2*)(Orow + 32 + 8 * g + 4 * h) = val;
    }
  }
}

extern "C" void kernel_launch(void* const* d_in, const int* in_sizes, int n_in,
                              void* d_out, int out_size, void* d_ws, size_t ws_size,
                              hipStream_t stream) {
  (void)in_sizes; (void)n_in; (void)out_size; (void)ws_size;
  const float* x      = (const float*)d_in[0];
  const float* w_qkv  = (const float*)d_in[1];
  const float* w_proj = (const float*)d_in[2];
  float* out = (float*)d_out;
  char* ws = (char*)d_ws;

  unsigned short* x_bf   = (unsigned short*)(ws);              // 16 MB (reused as attn_out)
  unsigned short* wqT    = (unsigned short*)(ws + 16777216);   // 6 MB
  unsigned short* wpT    = (unsigned short*)(ws + 23068672);   // 2 MB
  unsigned short* Qd     = (unsigned short*)(ws + 25165824);   // 16 MB
  unsigned short* Kd     = (unsigned short*)(ws + 41943040);   // 16 MB
  unsigned short* Vd     = (unsigned short*)(ws + 58720256);   // 16 MB
  unsigned short* Vt     = (unsigned short*)(ws + 75497472);   // 16 MB
  unsigned short* attn_o = x_bf;

  cvt_bf16_kernel<<<4096, 256, 0, stream>>>(x, x_bf, 8388608);
  transpose_w_kernel<<<dim3(96, 32), 256, 0, stream>>>(w_qkv, wqT, 1024, 3072);
  transpose_w_kernel<<<dim3(32, 32), 256, 0, stream>>>(w_proj, wpT, 1024, 1024);
  gemm_bt_kernel<8192, 3072, 1024, 0><<<dim3(24, 64), 256, 0, stream>>>(
      x_bf, wqT, Qd, Kd, Vd, nullptr);
  transpose_v_kernel<<<dim3(32, 64), 256, 0, stream>>>(Vd, Vt);
  attn_kernel<<<1024, 256, 0, stream>>>(Qd, Kd, Vt, attn_o);
  gemm_bt_kernel<8192, 1024, 1024, 1><<<dim3(8, 64), 256, 0, stream>>>(
      attn_o, wpT, nullptr, nullptr, nullptr, out);
}

// Round 9
// 218.304 us; speedup vs baseline: 1.1014x; 1.1014x over previous
//
#include <hip/hip_runtime.h>
#include <stdint.h>
#include <math.h>

typedef __attribute__((ext_vector_type(8))) short short8;
typedef __attribute__((ext_vector_type(4))) float f32x4;
typedef __attribute__((ext_vector_type(16))) float f32x16;

#define DEV __device__ __forceinline__

DEV unsigned short f2bf(float f) {
  union { float f; unsigned int u; } v; v.f = f;
  return (unsigned short)((v.u + 0x7FFFu + ((v.u >> 16) & 1u)) >> 16);
}

DEV unsigned int pkbf(float a, float b) {  // low16 = bf16(a), high16 = bf16(b)
  unsigned int r;
  asm("v_cvt_pk_bf16_f32 %0, %1, %2" : "=v"(r) : "v"(a), "v"(b));
  return r;
}

#if __has_builtin(__builtin_amdgcn_permlane32_swap)
DEV float redmax32(float v) {
  typedef __attribute__((ext_vector_type(2))) unsigned int uint2v;
  union { float f; unsigned int u; } c; c.f = v;
  uint2v r = __builtin_amdgcn_permlane32_swap(c.u, c.u, false, false);
  union { unsigned int u; float f; } a, b; a.u = r[0]; b.u = r[1];
  return fmaxf(a.f, b.f);
}
DEV float redsum32(float v) {
  typedef __attribute__((ext_vector_type(2))) unsigned int uint2v;
  union { float f; unsigned int u; } c; c.f = v;
  uint2v r = __builtin_amdgcn_permlane32_swap(c.u, c.u, false, false);
  union { unsigned int u; float f; } a, b; a.u = r[0]; b.u = r[1];
  return a.f + b.f;
}
#else
DEV float redmax32(float v) { return fmaxf(v, __shfl_xor(v, 32, 64)); }
DEV float redsum32(float v) { return v + __shfl_xor(v, 32, 64); }
#endif

DEV void gld16(const void* g, void* lds) {
  __builtin_amdgcn_global_load_lds(
      (const __attribute__((address_space(1))) unsigned int*)g,
      (__attribute__((address_space(3))) unsigned int*)lds, 16, 0, 0);
}

// ---------------- fp32 -> bf16 convert (8 elems/thread) ----------------
__global__ __launch_bounds__(256) void cvt_bf16_kernel(
    const float* __restrict__ in, unsigned short* __restrict__ out, int n) {
  int i = (blockIdx.x * 256 + threadIdx.x) * 8;
  if (i >= n) return;
  const float4 a = *(const float4*)(in + i);
  const float4 b = *(const float4*)(in + i + 4);
  short8 o;
  o[0] = (short)f2bf(a.x); o[1] = (short)f2bf(a.y);
  o[2] = (short)f2bf(a.z); o[3] = (short)f2bf(a.w);
  o[4] = (short)f2bf(b.x); o[5] = (short)f2bf(b.y);
  o[6] = (short)f2bf(b.z); o[7] = (short)f2bf(b.w);
  *(short8*)(out + i) = o;
}

// ------------- transpose fp32 (K x N) -> bf16 (N x K) ------------------
__global__ __launch_bounds__(256) void transpose_w_kernel(
    const float* __restrict__ in, unsigned short* __restrict__ out,
    int Kdim, int Ndim) {
  __shared__ float t[32][33];
  const int nb = blockIdx.x * 32, kb = blockIdx.y * 32;
  const int tx = threadIdx.x & 31, ty = threadIdx.x >> 5;  // ty 0..7
#pragma unroll
  for (int i = 0; i < 32; i += 8)
    t[ty + i][tx] = in[(size_t)(kb + ty + i) * Ndim + nb + tx];
  __syncthreads();
#pragma unroll
  for (int i = 0; i < 32; i += 8)
    out[(size_t)(nb + ty + i) * Kdim + kb + tx] = f2bf(t[tx][ty + i]);
}

// --------- transpose V (bh, s, 64) bf16 -> Vts (bh, 64, s') bf16 -------
// s' applies perm16 = swap bits 2,3 of (s mod 16) so that PV B-fragments
// are direct packs of the S^T D-fragment (no cross-lane exchange needed).
__global__ __launch_bounds__(256) void transpose_v_kernel(
    const unsigned short* __restrict__ V, unsigned short* __restrict__ Vt) {
  __shared__ __align__(16) unsigned short t[64][72];
  const int bh = blockIdx.y, s0 = blockIdx.x * 64;
  const int tid = threadIdx.x;
  const unsigned short* src = V + ((size_t)bh * 2048 + s0) * 64;
#pragma unroll
  for (int pass = 0; pass < 2; ++pass) {
    int r = (tid >> 3) + pass * 32;
    short8 v = *(const short8*)(src + r * 64 + (tid & 7) * 8);
    *(short8*)(&t[r][(tid & 7) * 8]) = v;
  }
  __syncthreads();
  unsigned short* dst = Vt + (size_t)bh * 64 * 2048 + s0;
#pragma unroll
  for (int pass = 0; pass < 2; ++pass) {
    int d = (tid >> 3) + pass * 32;
    int ss = (tid & 7) * 8;
    short8 v;
#pragma unroll
    for (int j = 0; j < 8; ++j) {
      const int u = ss + j;
      const int g = (u & ~12) | ((u & 4) << 1) | ((u & 8) >> 1);  // swap bits 2,3
      v[j] = (short)t[g][d];
    }
    *(short8*)(dst + (size_t)d * 2048 + ss) = v;
  }
}

// ---------------- GEMM: C(MxN) = A(MxK,bf16) * Bt(NxK,bf16)^T ----------
// ROUND-9 CHANGE (only one in this kernel): XCD-swizzled block remap.
// Bijective since nwg % 8 == 0 (1536 and 512). Each XCD gets a contiguous
// chunk of output tiles -> A-band fetched ~once, B L2-resident per XCD.
template<int M, int N, int K, int MODE>
__global__ __launch_bounds__(256)
void gemm_bt_kernel(const unsigned short* __restrict__ A,
                    const unsigned short* __restrict__ Bt,
                    unsigned short* __restrict__ Qd,
                    unsigned short* __restrict__ Kd,
                    unsigned short* __restrict__ Vd,
                    float* __restrict__ outC) {
  __shared__ __align__(16) unsigned short lsA[128 * 32];
  __shared__ __align__(16) unsigned short lsB[128 * 32];
  const int tid = threadIdx.x, wid = tid >> 6, lane = tid & 63;
  const int wr = wid >> 1, wc = wid & 1;
  constexpr int nx = N / 128;
  constexpr int nwg = (M / 128) * nx;
  static_assert(nwg % 8 == 0, "bijective XCD swizzle needs nwg % 8 == 0");
  int id = blockIdx.y * nx + blockIdx.x;
  id = (id & 7) * (nwg / 8) + (id >> 3);             // XCD-contiguous remap
  const int m0 = (id / nx) * 128, n0 = (id % nx) * 128;

  f32x4 acc[4][4] = {};

  const int rA = lane >> 2, kA = (lane & 3) * 8;
  for (int kt = 0; kt < K / 32; ++kt) {
    __syncthreads();
#pragma unroll
    for (int c = 0; c < 2; ++c) {
      const int q = c * 4 + wid;
      gld16(A  + (size_t)(m0 + q * 16 + rA) * K + kt * 32 + kA, lsA + q * 512);
      gld16(Bt + (size_t)(n0 + q * 16 + rA) * K + kt * 32 + kA, lsB + q * 512);
    }
    __syncthreads();
    short8 af[4], bfr[4];
#pragma unroll
    for (int i = 0; i < 4; ++i) {
      af[i]  = *(const short8*)(lsA + (wr * 64 + i * 16 + (lane & 15)) * 32 + (lane >> 4) * 8);
      bfr[i] = *(const short8*)(lsB + (wc * 64 + i * 16 + (lane & 15)) * 32 + (lane >> 4) * 8);
    }
#pragma unroll
    for (int i = 0; i < 4; ++i)
#pragma unroll
      for (int j = 0; j < 4; ++j)
        acc[i][j] = __builtin_amdgcn_mfma_f32_16x16x32_bf16(af[i], bfr[j], acc[i][j], 0, 0, 0);
  }

#pragma unroll
  for (int i = 0; i < 4; ++i) {
#pragma unroll
    for (int j = 0; j < 4; ++j) {
      const int rbase = m0 + wr * 64 + i * 16 + (lane >> 4) * 4;
      const int col = n0 + wc * 64 + j * 16 + (lane & 15);
      if constexpr (MODE == 0) {
        const int which = col >> 10, h = (col >> 6) & 15, d = col & 63;
        unsigned short* dst = which == 0 ? Qd : (which == 1 ? Kd : Vd);
        // Q pre-scaled by rsqrt(hd)*log2(e) so attention uses exp2 directly
        const float scale = which == 0 ? 0.18033688f : 1.0f;
#pragma unroll
        for (int ii = 0; ii < 4; ++ii) {
          const int r = rbase + ii, b = r >> 11, s = r & 2047;
          dst[((size_t)(b * 16 + h) * 2048 + s) * 64 + d] = f2bf(acc[i][j][ii] * scale);
        }
      } else {
#pragma unroll
        for (int ii = 0; ii < 4; ++ii)
          outC[(size_t)(rbase + ii) * N + col] = acc[i][j][ii];
      }
    }
  }
}

// ---------------- causal flash attention helpers (r6 verbatim) ----------
DEV void loadK4(const unsigned short* Kb, int krow0, int ql, int h, short8 kf[4]) {
#pragma unroll
  for (int s = 0; s < 4; ++s)
    kf[s] = *(const short8*)(Kb + (size_t)(krow0 + ql) * 64 + s * 16 + h * 8);
}
DEV void loadV4(const unsigned short* Vb, int kv0, int ql, int h, short8 vf[4]) {
#pragma unroll
  for (int t2 = 0; t2 < 2; ++t2)
#pragma unroll
    for (int sl = 0; sl < 2; ++sl)
      vf[t2 * 2 + sl] = *(const short8*)(Vb + (size_t)(t2 * 32 + ql) * 2048 + kv0 + sl * 16 + h * 8);
}

// One KV-tile step for NP parts. r6 verbatim + s_setprio(1) wrapped around
// the MFMA clusters (pure scheduler hint; T5/m191 regime: free-running waves).
template<int NP, bool MASK>
DEV void attn_step(int kv0, const short8 kf[4], const short8 qf[][4],
                   const int q0[], const short8 vf[4],
                   float m[], float l[], f32x16 o[][2], int ql, int h) {
  // stage 1: S^T for all parts (independent MFMA chains)
  f32x16 st[NP];
  __builtin_amdgcn_s_setprio(1);
#pragma unroll
  for (int pp = 0; pp < NP; ++pp) {
    f32x16 s = {};
#pragma unroll
    for (int ss = 0; ss < 4; ++ss)
      s = __builtin_amdgcn_mfma_f32_32x32x16_bf16(kf[ss], qf[pp][ss], s, 0, 0, 0);
    st[pp] = s;
  }
  __builtin_amdgcn_s_setprio(0);
  if constexpr (MASK) {
#pragma unroll
    for (int r = 0; r < 16; ++r) {
      const int krow = (r & 3) + 8 * (r >> 2) + 4 * h;
      if (kv0 + krow > q0[0] + ql) st[0][r] = -INFINITY;
    }
  }
  // stage 2: tile maxes (independent trees)
  float pm[NP];
#pragma unroll
  for (int pp = 0; pp < NP; ++pp) {
    float a = fmaxf(fmaxf(fmaxf(st[pp][0], st[pp][1]), fmaxf(st[pp][2], st[pp][3])),
                    fmaxf(fmaxf(st[pp][4], st[pp][5]), fmaxf(st[pp][6], st[pp][7])));
    a = fmaxf(a, fmaxf(fmaxf(fmaxf(st[pp][8], st[pp][9]), fmaxf(st[pp][10], st[pp][11])),
                       fmaxf(fmaxf(st[pp][12], st[pp][13]), fmaxf(st[pp][14], st[pp][15]))));
    pm[pp] = redmax32(a);
  }
  // stage 3: combined defer-max rescale (one branch for all parts;
  // false-positive rescale is exact: exp2f(0) == 1)
  bool need = false;
#pragma unroll
  for (int pp = 0; pp < NP; ++pp) need = need || (pm[pp] > m[pp] + 11.5f);
  if (__any(need)) {
#pragma unroll
    for (int pp = 0; pp < NP; ++pp) {
      const float mn = fmaxf(m[pp], pm[pp]);
      const float al = exp2f(m[pp] - mn);
      m[pp] = mn;
      l[pp] *= al;
#pragma unroll
      for (int r = 0; r < 16; ++r) { o[pp][0][r] *= al; o[pp][1][r] *= al; }
    }
  }
  // stage 4: exp2 + sum + pack per part (p lifetime local to pp)
  union pk_t { unsigned int u[4]; short8 s8; };
  pk_t f0[NP], f1[NP];
#pragma unroll
  for (int pp = 0; pp < NP; ++pp) {
    float p[16];
#pragma unroll
    for (int r = 0; r < 16; ++r) p[r] = exp2f(st[pp][r] - m[pp]);
    float ps = ((p[0] + p[1]) + (p[2] + p[3])) + ((p[4] + p[5]) + (p[6] + p[7]));
    ps += ((p[8] + p[9]) + (p[10] + p[11])) + ((p[12] + p[13]) + (p[14] + p[15]));
    l[pp] += redsum32(ps);
#pragma unroll
    for (int i = 0; i < 4; ++i) {
      f0[pp].u[i] = pkbf(p[2 * i], p[2 * i + 1]);
      f1[pp].u[i] = pkbf(p[8 + 2 * i], p[9 + 2 * i]);
    }
  }
  // stage 5: PV (2*NP independent MFMA chains of depth 2)
  __builtin_amdgcn_s_setprio(1);
#pragma unroll
  for (int pp = 0; pp < NP; ++pp) {
    o[pp][0] = __builtin_amdgcn_mfma_f32_32x32x16_bf16(vf[0], f0[pp].s8, o[pp][0], 0, 0, 0);
    o[pp][0] = __builtin_amdgcn_mfma_f32_32x32x16_bf16(vf[1], f1[pp].s8, o[pp][0], 0, 0, 0);
    o[pp][1] = __builtin_amdgcn_mfma_f32_32x32x16_bf16(vf[2], f0[pp].s8, o[pp][1], 0, 0, 0);
    o[pp][1] = __builtin_amdgcn_mfma_f32_32x32x16_bf16(vf[3], f1[pp].s8, o[pp][1], 0, 0, 0);
  }
  __builtin_amdgcn_s_setprio(0);
}

// ---------------- causal flash attention (r6 structure verbatim) --------
// grid 512 1-D, XCD-swizzled decode (bh = id&63 -> all 8 walkers of a bh on
// one XCD; K/V L2-resident). Wave owns q-tiles qtA = w*4+wid (0..31) and
// qtB = 63-qtA: 65 tile-parts, uniform. NO barrier, no dummy iterations.
// Four branch-free segments: [0,qtA) dual-part, {qtA} dual+maskA,
// (qtA,qtB) B-only, {qtB} B+maskB. V loaded in-tile; K prefetched 1 ahead.
__global__ __launch_bounds__(256, 2)
void attn_kernel(const unsigned short* __restrict__ Q,
                 const unsigned short* __restrict__ Kc,
                 const unsigned short* __restrict__ Vts,
                 unsigned short* __restrict__ O) {
  const int bh = blockIdx.x & 63;
  const int w  = blockIdx.x >> 6;            // 0..7, walker 0 = heaviest
  const int wid = threadIdx.x >> 6, lane = threadIdx.x & 63;
  const int ql = lane & 31, h = lane >> 5;
  const int qtA = w * 4 + wid;               // 0..31
  const int qtB = 63 - qtA;                  // 32..63
  const int q0[2] = {qtA * 32, qtB * 32};

  const unsigned short* Qb = Q   + (size_t)bh * 2048 * 64;
  const unsigned short* Kb = Kc  + (size_t)bh * 2048 * 64;
  const unsigned short* Vb = Vts + (size_t)bh * 64 * 2048;

  short8 qf[2][4];
#pragma unroll
  for (int pp = 0; pp < 2; ++pp)
#pragma unroll
    for (int s = 0; s < 4; ++s)
      qf[pp][s] = *(const short8*)(Qb + (size_t)(q0[pp] + ql) * 64 + s * 16 + h * 8);

  f32x16 o[2][2] = {};               // [part][d-half], O^T: col q, rows d
  float m[2] = {-INFINITY, -INFINITY};
  float l[2] = {0.f, 0.f};

  short8 kf[4], kn[4], vf[4];
  loadK4(Kb, 0, ql, h, kf);

  // segment 1: t in [0, qtA) -- both parts, no mask
  for (int t = 0; t < qtA; ++t) {
    const int kv0 = t * 32;
    loadV4(Vb, kv0, ql, h, vf);
    loadK4(Kb, kv0 + 32, ql, h, kn);           // <= 992: in-bounds
    attn_step<2, false>(kv0, kf, qf, q0, vf, m, l, o, ql, h);
#pragma unroll
    for (int s = 0; s < 4; ++s) kf[s] = kn[s];
  }
  // segment 2: t = qtA -- both parts, mask part A (B unmasked: qtA < qtB)
  {
    const int kv0 = qtA * 32;
    loadV4(Vb, kv0, ql, h, vf);
    loadK4(Kb, kv0 + 32, ql, h, kn);           // <= 1024: in-bounds
    attn_step<2, true>(kv0, kf, qf, q0, vf, m, l, o, ql, h);
#pragma unroll
    for (int s = 0; s < 4; ++s) kf[s] = kn[s];
  }
  // segment 3: t in (qtA, qtB) -- part B only
  for (int t = qtA + 1; t < qtB; ++t) {
    const int kv0 = t * 32;
    loadV4(Vb, kv0, ql, h, vf);
    loadK4(Kb, kv0 + 32, ql, h, kn);           // t < qtB <= 63 -> <= 2016: in-bounds
    attn_step<1, false>(kv0, kf, &qf[1], &q0[1], vf, &m[1], &l[1], &o[1], ql, h);
#pragma unroll
    for (int s = 0; s < 4; ++s) kf[s] = kn[s];
  }
  // segment 4: t = qtB -- part B, masked, no prefetch
  {
    const int kv0 = qtB * 32;
    loadV4(Vb, kv0, ql, h, vf);
    attn_step<1, true>(kv0, kf, &qf[1], &q0[1], vf, &m[1], &l[1], &o[1], ql, h);
  }

  // epilogue: lane-local 1/l, store both parts
  const int b = bh >> 4, head = bh & 15;
#pragma unroll
  for (int pp = 0; pp < 2; ++pp) {
    const float inv = 1.0f / l[pp];
    unsigned short* Orow = O + ((size_t)(b * 2048 + q0[pp] + ql)) * 1024 + head * 64;
#pragma unroll
    for (int g = 0; g < 4; ++g) {
      {
        const unsigned int lo = pkbf(o[pp][0][g * 4 + 0] * inv, o[pp][0][g * 4 + 1] * inv);
        const unsigned int hi = pkbf(o[pp][0][g * 4 + 2] * inv, o[pp][0][g * 4 + 3] * inv);
        uint2 val; val.x = lo; val.y = hi;
        *(uint2*)(Orow + 8 * g + 4 * h) = val;
      }
      {
        const unsigned int lo = pkbf(o[pp][1][g * 4 + 0] * inv, o[pp][1][g * 4 + 1] * inv);
        const unsigned int hi = pkbf(o[pp][1][g * 4 + 2] * inv, o[pp][1][g * 4 + 3] * inv);
        uint2 val; val.x = lo; val.y = hi;
        *(uint2*)(Orow + 32 + 8 * g + 4 * h) = val;
      }
    }
  }
}

extern "C" void kernel_launch(void* const* d_in, const int* in_sizes, int n_in,
                              void* d_out, int out_size, void* d_ws, size_t ws_size,
                              hipStream_t stream) {
  (void)in_sizes; (void)n_in; (void)out_size; (void)ws_size;
  const float* x      = (const float*)d_in[0];
  const float* w_qkv  = (const float*)d_in[1];
  const float* w_proj = (const float*)d_in[2];
  float* out = (float*)d_out;
  char* ws = (char*)d_ws;

  unsigned short* x_bf   = (unsigned short*)(ws);              // 16 MB (reused as attn_out)
  unsigned short* wqT    = (unsigned short*)(ws + 16777216);   // 6 MB
  unsigned short* wpT    = (unsigned short*)(ws + 23068672);   // 2 MB
  unsigned short* Qd     = (unsigned short*)(ws + 25165824);   // 16 MB
  unsigned short* Kd     = (unsigned short*)(ws + 41943040);   // 16 MB
  unsigned short* Vd     = (unsigned short*)(ws + 58720256);   // 16 MB
  unsigned short* Vt     = (unsigned short*)(ws + 75497472);   // 16 MB
  unsigned short* attn_o = x_bf;

  cvt_bf16_kernel<<<4096, 256, 0, stream>>>(x, x_bf, 8388608);
  transpose_w_kernel<<<dim3(96, 32), 256, 0, stream>>>(w_qkv, wqT, 1024, 3072);
  transpose_w_kernel<<<dim3(32, 32), 256, 0, stream>>>(w_proj, wpT, 1024, 1024);
  gemm_bt_kernel<8192, 3072, 1024, 0><<<dim3(24, 64), 256, 0, stream>>>(
      x_bf, wqT, Qd, Kd, Vd, nullptr);
  transpose_v_kernel<<<dim3(32, 64), 256, 0, stream>>>(Vd, Vt);
  attn_kernel<<<512, 256, 0, stream>>>(Qd, Kd, Vt, attn_o);
  gemm_bt_kernel<8192, 1024, 1024, 1><<<dim3(8, 64), 256, 0, stream>>>(
      attn_o, wpT, nullptr, nullptr, nullptr, out);
}